// Round 9
// baseline (18.938 us; speedup 1.0000x reference)
//
#include <hip/hip_runtime.h>

#define D_ 32
#define H_ 128
#define B_ 32
#define DT 1.0f   // single RK4 step over [0,1]

template<int N> struct IC { static constexpr int v = N; };

// ---- DPP cross-lane reduction over 8 consecutive lanes (no DS ops) ----
template<int CTRL>
__device__ __forceinline__ float qadd(float v) {
  int t = __builtin_amdgcn_update_dpp(0, __builtin_bit_cast(int, v), CTRL, 0xF, 0xF, true);
  return v + __builtin_bit_cast(float, t);
}
__device__ __forceinline__ float xor4add(float v) {
  int s = __builtin_bit_cast(int, v);
  int t = __builtin_amdgcn_update_dpp(0, s, 0x12C, 0xF, 0x5, true);  // ror:12 -> lanes 0-3,8-11
  t     = __builtin_amdgcn_update_dpp(t, s, 0x124, 0xF, 0xA, true);  // ror:4  -> lanes 4-7,12-15
  return v + __builtin_bit_cast(float, t);
}
__device__ __forceinline__ float red8(float v) { return xor4add(qadd<0x4E>(qadd<0xB1>(v))); }

// Precompute (input-independent):
//   P[i][k] = sum_d W1[i][d] * W3[d][k]  -> u-space propagation matrix
//   G[k][i] = W2[k][i] * P[i][k]         -> trace(J) = d2^T (G d1)
//   q[i]    = sum_d W1[i][d] * b3[d]
__global__ void g_precompute(const float* __restrict__ W1, const float* __restrict__ W2,
                             const float* __restrict__ W3, const float* __restrict__ b3,
                             float* __restrict__ G, float* __restrict__ P,
                             float* __restrict__ q) {
  const int i = blockIdx.x;
  const int k = threadIdx.x;
  const float* w1r = W1 + i*(D_+1);
  float m = 0.f;
  #pragma unroll
  for (int d = 0; d < D_; ++d) m += w1r[d] * W3[d*H_ + k];
  P[i*H_ + k] = m;
  G[k*H_ + i] = W2[k*H_ + i] * m;
  if (k == 0) {
    float s = 0.f;
    #pragma unroll
    for (int d = 0; d < D_; ++d) s += w1r[d] * b3[d];
    q[i] = s;
  }
}

// 4-wave solver: 256 threads, 1 wave/SIMD. Every thread holds W2, G, P 4x16 tiles
// (rows 4rg..4rg+3, cols 16cg..16cg+15, chunk-rotated) + a W3 1x16 epilogue tile.
// Owner lanes (cg<4) own row r=4rg+cg: u-state, h2/d2/gv/trace/hacc all register-local.
__global__ __launch_bounds__(256, 1)
void node_solve(const float* __restrict__ x,
                const float* __restrict__ W1, const float* __restrict__ b1,
                const float* __restrict__ W2, const float* __restrict__ b2,
                const float* __restrict__ W3, const float* __restrict__ b3,
                const float* __restrict__ G, const float* __restrict__ P,
                const float* __restrict__ q, float* __restrict__ out) {
  const int tid = threadIdx.x;
  const int b   = blockIdx.x;

  __shared__ __align__(16) float h1_l[H_];
  __shared__ __align__(16) float d1_l[H_];
  __shared__ __align__(16) float h2_l[H_];   // P3: owners store hacc here instead of h2
  __shared__ float tr_l[4];

  float wA[64];   // W2 tile
  float wG[64];   // G tile
  float wP[64];   // P tile
  float wE[16];   // W3 epilogue tile (row er, cols 16ec..+15, rotated)

  const int rg = tid >> 3;        // 0..31 -> rows 4rg..4rg+3
  const int cg = tid & 7;         // col chunk 16cg..16cg+15
  const int r  = 4*rg + cg;       // owned row (valid when cg<4)
  const int er = rg, ec = cg;     // epilogue: W3 row er (0..31), col chunk 16ec

  float zu = 0.f;                                    // u-space state (owners)
  float hacc = 0.f;                                  // sum wS*h2 (owners)
  float tracc = 0.f;                                 // sum wS*d2*gv (owners)
  float rqq = 0.f, rb1 = 0.f, w1t = 0.f, rb2 = 0.f;  // owner row constants
  float zr = 0.f, rb3 = 0.f;                         // epilogue row constants (ec==0)

  auto tanh_f = [](float u) {
    float e = exp2f(2.885390081777927f * u);
    return 1.0f - 2.0f * __builtin_amdgcn_rcpf(e + 1.0f);
  };

  // ---- weight tile loads (chunk-rotated for bank-clean LDS reads later) ----
  #pragma unroll
  for (int j = 0; j < 4; ++j) {
    const float* pw2 = W2 + (4*rg + j)*H_ + cg*16;
    const float* pg  = G  + (4*rg + j)*H_ + cg*16;
    const float* pp  = P  + (4*rg + j)*H_ + cg*16;
    #pragma unroll
    for (int k = 0; k < 4; ++k) {
      const int src = 4*((k + cg) & 3);
      #pragma unroll
      for (int e = 0; e < 4; ++e) {
        wA[16*j + 4*k + e] = pw2[src + e];
        wG[16*j + 4*k + e] = pg[src + e];
        wP[16*j + 4*k + e] = pp[src + e];
      }
    }
  }
  {
    const float* pe = W3 + er*H_ + ec*16;
    #pragma unroll
    for (int k = 0; k < 4; ++k) {
      const int src = 4*((k + ec) & 3);
      #pragma unroll
      for (int e = 0; e < 4; ++e) wE[4*k + e] = pe[src + e];
    }
    if (ec == 0) { zr = x[b*D_ + er]; rb3 = b3[er]; }
  }
  if (cg < 4) {
    rqq = q[r];
    rb1 = b1[r];
    rb2 = b2[r];
    w1t = W1[r*(D_+1) + D_];
    // init: zu = W1x . x0 ; seed h1/d1 at t=0 (t_eff = 1)
    float zu0 = 0.f;
    const float* w1r = W1 + r*(D_+1);
    const float* xb  = x + b*D_;
    #pragma unroll
    for (int d = 0; d < D_; ++d) zu0 += w1r[d] * xb[d];
    zu = zu0;
    float h = tanh_f(zu0 + w1t + rb1);
    h1_l[r] = h;
    d1_l[r] = 1.f - h*h;
  }
  __syncthreads();

  // Phase P (stage S): h2 = tanh(W2 h1 + b2) and gv = G d1, both on all threads.
  // Owners: trace partial (d2*gv local), hacc; S==3 stores hacc into h2_l.
  auto phaseP = [&](auto Sc) {
    constexpr int S = decltype(Sc)::v;
    constexpr float wS = (S==0 || S==3) ? 1.f : 2.f;
    float4 va[4], vb[4];
    #pragma unroll
    for (int k = 0; k < 4; ++k) {
      const int off = cg*16 + 4*((k + cg) & 3);
      va[k] = *reinterpret_cast<const float4*>(h1_l + off);
      vb[k] = *reinterpret_cast<const float4*>(d1_l + off);
    }
    float aW[4], aG[4];
    #pragma unroll
    for (int j = 0; j < 4; ++j) {
      float s0=0.f, s1=0.f, s2=0.f, s3=0.f;
      float t0=0.f, t1=0.f, t2=0.f, t3=0.f;
      #pragma unroll
      for (int k = 0; k < 4; ++k) {
        s0 += wA[16*j+4*k+0]*va[k].x;  t0 += wG[16*j+4*k+0]*vb[k].x;
        s1 += wA[16*j+4*k+1]*va[k].y;  t1 += wG[16*j+4*k+1]*vb[k].y;
        s2 += wA[16*j+4*k+2]*va[k].z;  t2 += wG[16*j+4*k+2]*vb[k].z;
        s3 += wA[16*j+4*k+3]*va[k].w;  t3 += wG[16*j+4*k+3]*vb[k].w;
      }
      aW[j] = red8((s0+s1)+(s2+s3));
      aG[j] = red8((t0+t1)+(t2+t3));
    }
    if (cg < 4) {
      float a = aW[0], g = aG[0];
      a = (cg == 1) ? aW[1] : a;  g = (cg == 1) ? aG[1] : g;
      a = (cg == 2) ? aW[2] : a;  g = (cg == 2) ? aG[2] : g;
      a = (cg == 3) ? aW[3] : a;  g = (cg == 3) ? aG[3] : g;
      const float h  = tanh_f(a + rb2);
      const float d2 = 1.f - h*h;
      tracc += wS * d2 * g;
      hacc  += wS * h;
      h2_l[r] = (S == 3) ? hacc : h;   // P3: stage hacc for epilogue (h2_3 unused)
    }
  };

  // Phase Q (stage S<3): Ku = -(P h2 + q); owners emit next-stage h1/d1.
  auto phaseQ = [&](auto Sc) {
    constexpr int S = decltype(Sc)::v;
    float4 vh[4];
    #pragma unroll
    for (int k = 0; k < 4; ++k)
      vh[k] = *reinterpret_cast<const float4*>(h2_l + cg*16 + 4*((k + cg) & 3));
    float aP[4];
    #pragma unroll
    for (int j = 0; j < 4; ++j) {
      float s0=0.f, s1=0.f, s2=0.f, s3=0.f;
      #pragma unroll
      for (int k = 0; k < 4; ++k) {
        s0 += wP[16*j+4*k+0]*vh[k].x;
        s1 += wP[16*j+4*k+1]*vh[k].y;
        s2 += wP[16*j+4*k+2]*vh[k].z;
        s3 += wP[16*j+4*k+3]*vh[k].w;
      }
      aP[j] = red8((s0+s1)+(s2+s3));
    }
    if (cg < 4) {
      float a = aP[0];
      a = (cg == 1) ? aP[1] : a;
      a = (cg == 2) ? aP[2] : a;
      a = (cg == 3) ? aP[3] : a;
      const float Ku = -(a + rqq);
      const float zb = zu + ((S == 2) ? DT : 0.5f*DT) * Ku;
      const float te = (S < 2) ? (1.0f - 0.5f*DT) : (1.0f - DT);
      const float h  = tanh_f(zb + w1t*te + rb1);
      h1_l[r] = h;
      d1_l[r] = 1.f - h*h;
    }
  };

  // ---- single RK4 step over [0,1] ----
  phaseP(IC<0>{}); __syncthreads(); phaseQ(IC<0>{}); __syncthreads();
  phaseP(IC<1>{}); __syncthreads(); phaseQ(IC<1>{}); __syncthreads();
  phaseP(IC<2>{}); __syncthreads(); phaseQ(IC<2>{}); __syncthreads();
  phaseP(IC<3>{});

  // trace: per-wave butterfly (owners hold partials), one slot per wave
  {
    float v = tracc;
    #pragma unroll
    for (int m = 1; m < 64; m <<= 1) v += __shfl_xor(v, m);
    if ((tid & 63) == 0) tr_l[tid >> 6] = v;
  }
  __syncthreads();

  // ---- epilogue ----
  // x(1) = x0 - (DT/6) * W3 . hacc - b3   (hacc staged in h2_l; sum of wS = 6)
  {
    float4 vh[4];
    #pragma unroll
    for (int k = 0; k < 4; ++k)
      vh[k] = *reinterpret_cast<const float4*>(h2_l + ec*16 + 4*((k + ec) & 3));
    float s0=0.f, s1=0.f, s2=0.f, s3=0.f;
    #pragma unroll
    for (int k = 0; k < 4; ++k) {
      s0 += wE[4*k+0]*vh[k].x;
      s1 += wE[4*k+1]*vh[k].y;
      s2 += wE[4*k+2]*vh[k].z;
      s3 += wE[4*k+3]*vh[k].w;
    }
    float acc = red8((s0+s1)+(s2+s3));
    if (ec == 0) out[b*D_ + er] = zr - (DT/6.0f)*acc - rb3;
  }
  if (tid == 0)
    out[B_*D_ + b] = -(DT/6.0f) * (tr_l[0] + tr_l[1] + tr_l[2] + tr_l[3]);
}

extern "C" void kernel_launch(void* const* d_in, const int* in_sizes, int n_in,
                              void* d_out, int out_size, void* d_ws, size_t ws_size,
                              hipStream_t stream) {
  const float* x  = (const float*)d_in[0];
  const float* W1 = (const float*)d_in[1];
  const float* b1 = (const float*)d_in[2];
  const float* W2 = (const float*)d_in[3];
  const float* b2 = (const float*)d_in[4];
  const float* W3 = (const float*)d_in[5];
  const float* b3 = (const float*)d_in[6];
  float* out = (float*)d_out;
  float* G = (float*)d_ws;
  float* P = G + H_*H_;
  float* q = P + H_*H_;

  hipLaunchKernelGGL(g_precompute, dim3(H_), dim3(H_), 0, stream, W1, W2, W3, b3, G, P, q);
  hipLaunchKernelGGL(node_solve, dim3(B_), dim3(256), 0, stream,
                     x, W1, b1, W2, b2, W3, b3, G, P, q, out);
}

// Round 10
// 16.835 us; speedup vs baseline: 1.1249x; 1.1249x over previous
//
#include <hip/hip_runtime.h>

#define D_ 32
#define H_ 128
#define B_ 32
#define DT 1.0f   // single RK4 step over [0,1]

template<int N> struct IC { static constexpr int v = N; };

// ---- DPP cross-lane reduction (no DS ops) ----
template<int CTRL>
__device__ __forceinline__ float qadd(float v) {
  int t = __builtin_amdgcn_update_dpp(0, __builtin_bit_cast(int, v), CTRL, 0xF, 0xF, true);
  return v + __builtin_bit_cast(float, t);
}
__device__ __forceinline__ float xor4add(float v) {
  int s = __builtin_bit_cast(int, v);
  int t = __builtin_amdgcn_update_dpp(0, s, 0x12C, 0xF, 0x5, true);  // ror:12 -> lanes 0-3,8-11
  t     = __builtin_amdgcn_update_dpp(t, s, 0x124, 0xF, 0xA, true);  // ror:4  -> lanes 4-7,12-15
  return v + __builtin_bit_cast(float, t);
}
__device__ __forceinline__ float red8(float v) { return xor4add(qadd<0x4E>(qadd<0xB1>(v))); }
__device__ __forceinline__ float red4(float v) { return qadd<0x4E>(qadd<0xB1>(v)); }

// Precompute (input-independent):
//   P[i][k] = sum_d W1[i][d] * W3[d][k]  -> u-space propagation matrix
//   G[k][i] = W2[k][i] * P[i][k]         -> trace(J) = d2^T (G d1)
//   q[i]    = sum_d W1[i][d] * b3[d]
__global__ void g_precompute(const float* __restrict__ W1, const float* __restrict__ W2,
                             const float* __restrict__ W3, const float* __restrict__ b3,
                             float* __restrict__ G, float* __restrict__ P,
                             float* __restrict__ q) {
  const int i = blockIdx.x;
  const int k = threadIdx.x;
  const float* w1r = W1 + i*(D_+1);
  float m = 0.f;
  #pragma unroll
  for (int d = 0; d < D_; ++d) m += w1r[d] * W3[d*H_ + k];
  P[i*H_ + k] = m;
  G[k*H_ + i] = W2[k*H_ + i] * m;
  if (k == 0) {
    float s = 0.f;
    #pragma unroll
    for (int d = 0; d < D_; ++d) s += w1r[d] * b3[d];
    q[i] = s;
  }
}

// 8-wave solver (r8 structure + folded epilogue):
//  waves 0-3: W2 tiles (phase P: h2) and P tiles (phase Q: Ku, u-state owners)
//  waves 4-7: G tiles (phase P: gv); waves 4-5 also W3 quarter-rows for the
//             x-quadrature (computed during Q2 + after P3); wave 6: trace taps.
__global__ __launch_bounds__(512)
void node_solve(const float* __restrict__ x,
                const float* __restrict__ W1, const float* __restrict__ b1,
                const float* __restrict__ W2, const float* __restrict__ b2,
                const float* __restrict__ W3, const float* __restrict__ b3,
                const float* __restrict__ G, const float* __restrict__ P,
                const float* __restrict__ q, float* __restrict__ out) {
  const int tid = threadIdx.x;
  const int b   = blockIdx.x;

  __shared__ __align__(16) float h1_l[H_];
  __shared__ __align__(16) float d1_l[H_];
  __shared__ __align__(16) float h2_l[H_];
  __shared__ __align__(16) float d2_l[H_];
  __shared__ __align__(16) float gv_l[H_];
  __shared__ __align__(16) float hq_l[H_];   // hacc012 staging (written P2, read Q2)

  float wA[64];    // phase P tile (waves 0-3: W2, waves 4-7: G), chunk-rotated
  float wP[64];    // phase Q tile of P (waves 0-3)
  float wB3[32];   // W3 quarter-row (waves 4-5), chunk-rotated
  float rb3 = 0.f;

  const int lt = tid & 255;
  const int rg = lt >> 3;          // group: rows 4rg..4rg+3
  const int cg = lt & 7;           // 8 threads per group, 16 cols each
  const int myrow = 4*rg + cg;     // owned row (valid when cg < 4)
  const int r3 = (tid - 256) >> 2; // W3 row (tid in [256,384))
  const int c3 = tid & 3;

  float zu = 0.f;                                    // u-space state (waves 0-3, cg<4)
  float hacc = 0.f;                                  // h0+2h1+2h2 (owners)
  float eacc = 0.f;                                  // W3 . hacc012 partial (waves 4-5)
  float rqq = 0.f, rb1 = 0.f, w1t = 0.f, rb2 = 0.f;  // owner row constants
  float zr = 0.f;                                    // x0 (waves 4-5)
  float tracc = 0.f;                                 // trace partials (wave 6)

  auto tanh_f = [](float u) {
    float e = exp2f(2.885390081777927f * u);
    return 1.0f - 2.0f * __builtin_amdgcn_rcpf(e + 1.0f);
  };

  // ---- weight loads (rotated for bank-clean LDS reads later) ----
  {
    const float* Wsrc = (tid < 256) ? W2 : G;
    #pragma unroll
    for (int j = 0; j < 4; ++j) {
      const float* p = Wsrc + (4*rg + j)*H_ + cg*16;
      #pragma unroll
      for (int k = 0; k < 4; ++k) {
        const int src = 4*((k + cg) & 3);
        #pragma unroll
        for (int e = 0; e < 4; ++e) wA[16*j + 4*k + e] = p[src + e];
      }
    }
  }
  if (tid < 256) {
    #pragma unroll
    for (int j = 0; j < 4; ++j) {
      const float* p = P + (4*rg + j)*H_ + cg*16;
      #pragma unroll
      for (int k = 0; k < 4; ++k) {
        const int src = 4*((k + cg) & 3);
        #pragma unroll
        for (int e = 0; e < 4; ++e) wP[16*j + 4*k + e] = p[src + e];
      }
    }
    if (cg < 4) {
      rqq = q[myrow];
      rb1 = b1[myrow];
      rb2 = b2[myrow];
      w1t = W1[myrow*(D_+1) + D_];
      // init: zu = W1x . x0 ; seed h1/d1 at t=0 (t_eff = 1)
      float zu0 = 0.f;
      const float* w1r = W1 + myrow*(D_+1);
      const float* xb  = x + b*D_;
      #pragma unroll
      for (int d = 0; d < D_; ++d) zu0 += w1r[d] * xb[d];
      zu = zu0;
      float h = tanh_f(zu0 + w1t + rb1);
      h1_l[myrow] = h;
      d1_l[myrow] = 1.f - h*h;
    }
  } else if (tid < 384) {
    const float* p = W3 + r3*H_ + c3*32;
    #pragma unroll
    for (int jj = 0; jj < 8; ++jj) {
      const int src = 4*((jj + 2*c3) & 7);
      #pragma unroll
      for (int e = 0; e < 4; ++e) wB3[4*jj + e] = p[src + e];
    }
    rb3 = b3[r3];
    zr  = x[b*D_ + r3];
  }
  __syncthreads();

  // Phase P (stage S): h2 = tanh(W2 h1 + b2) (waves 0-3) || gv = G d1 (waves 4-7).
  // Owners: hacc (S<3); S==2 stashes hacc012 into hq_l for the Q2 quadrature.
  auto phaseP = [&](auto Sc) {
    constexpr int S = decltype(Sc)::v;
    constexpr float wS = (S==0 || S==3) ? 1.f : 2.f;
    const float* vec  = (tid < 256) ? h1_l : d1_l;
    const float* base = vec + cg*16;
    float4 va[4];
    #pragma unroll
    for (int k = 0; k < 4; ++k)
      va[k] = *reinterpret_cast<const float4*>(base + 4*((k + cg) & 3));
    float accv[4];
    #pragma unroll
    for (int j = 0; j < 4; ++j) {
      float s0=0.f, s1=0.f, s2=0.f, s3=0.f;
      #pragma unroll
      for (int k = 0; k < 4; ++k) {
        s0 += wA[16*j+4*k+0]*va[k].x;
        s1 += wA[16*j+4*k+1]*va[k].y;
        s2 += wA[16*j+4*k+2]*va[k].z;
        s3 += wA[16*j+4*k+3]*va[k].w;
      }
      accv[j] = red8((s0+s1)+(s2+s3));
    }
    if (cg < 4) {
      float a = accv[0];
      a = (cg == 1) ? accv[1] : a;
      a = (cg == 2) ? accv[2] : a;
      a = (cg == 3) ? accv[3] : a;
      if (tid < 256) {
        float h = tanh_f(a + rb2);
        h2_l[myrow] = h;
        d2_l[myrow] = 1.f - h*h;
        if constexpr (S < 3) hacc += wS * h;
        if constexpr (S == 2) hq_l[myrow] = hacc;   // h0+2h1+2h2
      } else {
        gv_l[myrow] = a;
      }
    }
  };

  // Phase Q (stage S<3): waves 0-3: Ku = -(P h2 + q), owners emit next h1/d1;
  // wave 6: trace tap (d2 . gv of stage S); waves 4-5 at S==2: eacc = W3 . hq.
  auto phaseQ = [&](auto Sc) {
    constexpr int S = decltype(Sc)::v;
    constexpr float wS = (S==0) ? 1.f : 2.f;
    if (tid < 256) {
      const float* base = h2_l + cg*16;
      float4 va[4];
      #pragma unroll
      for (int k = 0; k < 4; ++k)
        va[k] = *reinterpret_cast<const float4*>(base + 4*((k + cg) & 3));
      float accv[4];
      #pragma unroll
      for (int j = 0; j < 4; ++j) {
        float s0=0.f, s1=0.f, s2=0.f, s3=0.f;
        #pragma unroll
        for (int k = 0; k < 4; ++k) {
          s0 += wP[16*j+4*k+0]*va[k].x;
          s1 += wP[16*j+4*k+1]*va[k].y;
          s2 += wP[16*j+4*k+2]*va[k].z;
          s3 += wP[16*j+4*k+3]*va[k].w;
        }
        accv[j] = red8((s0+s1)+(s2+s3));
      }
      if (cg < 4) {
        float a = accv[0];
        a = (cg == 1) ? accv[1] : a;
        a = (cg == 2) ? accv[2] : a;
        a = (cg == 3) ? accv[3] : a;
        const float Ku = -(a + rqq);
        const float zb = zu + ((S == 2) ? DT : 0.5f*DT) * Ku;
        const float te = (S < 2) ? (1.0f - 0.5f*DT) : (1.0f - DT);
        const float h  = tanh_f(zb + w1t*te + rb1);
        h1_l[myrow] = h;
        d1_l[myrow] = 1.f - h*h;
      }
    } else if (tid < 384) {
      if constexpr (S == 2) {   // x-quadrature part 1: W3 . (h0+2h1+2h2)
        const float* base = hq_l + c3*32;
        float s0=0.f, s1=0.f, s2=0.f, s3=0.f;
        #pragma unroll
        for (int jj = 0; jj < 8; ++jj) {
          float4 v = *reinterpret_cast<const float4*>(base + 4*((jj + 2*c3) & 7));
          s0 += wB3[4*jj+0]*v.x;
          s1 += wB3[4*jj+1]*v.y;
          s2 += wB3[4*jj+2]*v.z;
          s3 += wB3[4*jj+3]*v.w;
        }
        eacc = (s0+s1)+(s2+s3);
      }
    } else if (tid < 448) {
      const int l = tid - 384;
      tracc += wS * (d2_l[l]*gv_l[l] + d2_l[l+64]*gv_l[l+64]);
    }
  };

  // ---- single RK4 step over [0,1] ----
  phaseP(IC<0>{}); __syncthreads(); phaseQ(IC<0>{}); __syncthreads();
  phaseP(IC<1>{}); __syncthreads(); phaseQ(IC<1>{}); __syncthreads();
  phaseP(IC<2>{}); __syncthreads(); phaseQ(IC<2>{}); __syncthreads();
  phaseP(IC<3>{}); __syncthreads();

  // ---- final: x-quadrature part 2 (W3 . h3) + trace finish, fully barriered ----
  if (tid >= 256 && tid < 384) {
    const float* base = h2_l + c3*32;   // h2_l holds h3
    float s0=0.f, s1=0.f, s2=0.f, s3=0.f;
    #pragma unroll
    for (int jj = 0; jj < 8; ++jj) {
      float4 v = *reinterpret_cast<const float4*>(base + 4*((jj + 2*c3) & 7));
      s0 += wB3[4*jj+0]*v.x;
      s1 += wB3[4*jj+1]*v.y;
      s2 += wB3[4*jj+2]*v.z;
      s3 += wB3[4*jj+3]*v.w;
    }
    float acc = red4(eacc + (s0+s1)+(s2+s3));
    // x(1) = x0 - (1/6) * W3 . (h0+2h1+2h2+h3) - b3
    if (c3 == 0) out[b*D_ + r3] = zr - (DT/6.0f)*acc - rb3;
  } else if (tid >= 384 && tid < 448) {
    const int l = tid - 384;
    float v = tracc + (d2_l[l]*gv_l[l] + d2_l[l+64]*gv_l[l+64]);  // stage-3 tap, w=1
    #pragma unroll
    for (int m = 1; m < 64; m <<= 1) v += __shfl_xor(v, m);
    if (tid == 384) out[B_*D_ + b] = -(DT/6.0f) * v;   // log_px = -∫ trace
  }
}

extern "C" void kernel_launch(void* const* d_in, const int* in_sizes, int n_in,
                              void* d_out, int out_size, void* d_ws, size_t ws_size,
                              hipStream_t stream) {
  const float* x  = (const float*)d_in[0];
  const float* W1 = (const float*)d_in[1];
  const float* b1 = (const float*)d_in[2];
  const float* W2 = (const float*)d_in[3];
  const float* b2 = (const float*)d_in[4];
  const float* W3 = (const float*)d_in[5];
  const float* b3 = (const float*)d_in[6];
  float* out = (float*)d_out;
  float* G = (float*)d_ws;
  float* P = G + H_*H_;
  float* q = P + H_*H_;

  hipLaunchKernelGGL(g_precompute, dim3(H_), dim3(H_), 0, stream, W1, W2, W3, b3, G, P, q);
  hipLaunchKernelGGL(node_solve, dim3(B_), dim3(512), 0, stream,
                     x, W1, b1, W2, b2, W3, b3, G, P, q, out);
}